// Round 9
// baseline (1367.660 us; speedup 1.0000x reference)
//
#include <hip/hip_runtime.h>
#include <hip/hip_bf16.h>
#include <stdint.h>

typedef __attribute__((ext_vector_type(8)))  short short8;
typedef __attribute__((ext_vector_type(16))) float f32x16;

#define NROWS 500000
#define NCHUNK 15625         // 500000 / 32 rows per chunk (exact, no tail)
#define NBLK 256
#define NTHR 1024            // 16 waves/block -> 4 waves/SIMD (was 2)
#define NWAVE_TOT (NBLK * 16)

// swap bits 2<->3 (involution); aligns MFMA D-layout (row=(reg&3)+8(reg>>2)+4hi)
// with B-frag k-layout (k = 16kt + 8hi + j). HW-verified r6 (absmax 0.047).
#define SW(v) ((((v) & ~12u)) | (((v) & 4u) << 1) | (((v) & 8u) >> 1))

// LDS map (bytes) — identical to r6
#define A2_OFF   0           // 131072 : W2 A-frags, frag(kt,mt) @ (kt*8+mt)*1024 + l*16
#define A1_OFF   131072      // 4096   : [W1t|b1] A-frags, lo lanes only: fr*512 + c*16
#define Z_OFF    135168      // 16     : shared zero block (broadcast reads)
#define A3_OFF   135184      // 1536   : W3 A-frags: kt*96 + (hi*3+c)*16 (c<3)
#define SCR_OFF  136720      // 16384  : packing scratch (16 W2 rows fp32)
#define LDS_TOTAL 153104

__device__ __forceinline__ uint32_t cvtpk(float lo, float hi) {
    uint32_t r;
    asm("v_cvt_pk_bf16_f32 %0, %1, %2" : "=v"(r) : "v"(lo), "v"(hi));
    return r;
}

__global__ __launch_bounds__(NTHR, 4) void fused_kernel(
    const float* __restrict__ x,  const float* __restrict__ W1,
    const float* __restrict__ b1, const float* __restrict__ W2,
    const float* __restrict__ b2, const float* __restrict__ W3,
    const float* __restrict__ b3, float* __restrict__ out)
{
    extern __shared__ char smem[];
    uint4* frag4 = (uint4*)(smem + A2_OFF);
    float* scrf  = (float*)(smem + SCR_OFF);
    uint4* scr4  = (uint4*)(smem + SCR_OFF);

    const int tid = threadIdx.x;
    const int l   = tid & 63;
    const int hi  = l >> 5;       // k-half within frags
    const int c   = l & 31;       // batch column / A-row within tile

    // ================= one-time packing (r6 machinery, 1024-thread adapted) =====
    {
        int fr = tid >> 6, l2 = tid & 63;
        if (fr < 8 && l2 < 32) {
            int row = fr * 32 + l2;
            uint4 v;
            v.x = cvtpk(W1[row], W1[256 + row]);
            v.y = cvtpk(W1[512 + row], b1[row]);
            v.z = 0; v.w = 0;
            ((uint4*)(smem + A1_OFF))[fr * 32 + l2] = v;
        }
        if (tid == 1023) ((uint4*)(smem + Z_OFF))[0] = make_uint4(0, 0, 0, 0);
        if (tid < 96) {
            int fr3 = tid / 6, rem = tid % 6, hi2 = rem / 3, c2 = rem % 3;
            int kb = 16 * fr3 + 8 * hi2;
            uint4 v;
            v.x = cvtpk(W3[(kb + 0) * 3 + c2], W3[(kb + 1) * 3 + c2]);
            v.y = cvtpk(W3[(kb + 2) * 3 + c2], W3[(kb + 3) * 3 + c2]);
            v.z = cvtpk(W3[(kb + 4) * 3 + c2], W3[(kb + 5) * 3 + c2]);
            v.w = cvtpk(W3[(kb + 6) * 3 + c2], W3[(kb + 7) * 3 + c2]);
            ((uint4*)(smem + A3_OFF))[fr3 * 6 + rem] = v;
        }
    }
    // W2 -> A2-frags: 16 passes, 16 rows (16 KB) staged per pass by all 1024 threads
    const uint4* gw2 = (const uint4*)W2;
    for (int kt = 0; kt < 16; ++kt) {
        __syncthreads();
        scr4[tid] = gw2[kt * 1024 + tid];      // 1024 uint4 = 16 rows, coalesced
        __syncthreads();
        if (tid < 512) {
            int mt = tid >> 6, l2 = tid & 63, hi2 = l2 >> 5, c2 = l2 & 31;
            int col = 32 * mt + (int)SW((unsigned)c2);
            float f[8];
#pragma unroll
            for (int j = 0; j < 8; ++j) {
                int lrow = 8 * (j >> 2) + 4 * hi2 + (j & 3);
                f[j] = scrf[lrow * 256 + col];
            }
            uint4 v;
            v.x = cvtpk(f[0], f[1]); v.y = cvtpk(f[2], f[3]);
            v.z = cvtpk(f[4], f[5]); v.w = cvtpk(f[6], f[7]);
            frag4[(kt * 8 + mt) * 64 + l2] = v;
        }
    }
    __syncthreads();   // LDS read-only from here; waves fully independent

    // ================= per-lane held constants =================
    const f32x16 Z = {0,0,0,0,0,0,0,0,0,0,0,0,0,0,0,0};
    uint32_t b2pk[8];                 // bf16(b2[SW(32mt+c)]), lo lanes only
#pragma unroll
    for (int mt = 0; mt < 8; ++mt)
        b2pk[mt] = hi ? 0u : cvtpk(b2[32 * mt + (int)SW((unsigned)c)], 0.0f);
    union { short8 s8; uint32_t u[4]; } bB;   // bias B-frag: B[0][*]=1 (lo lanes)
    bB.u[0] = hi ? 0u : 0x3F80u; bB.u[1] = 0; bB.u[2] = 0; bB.u[3] = 0;
    const short8 biasB = bB.s8;
    const float b30 = b3[0], b31 = b3[1], b32 = b3[2];

    const int a1step = hi ? 0 : 512;
    const int a1base = hi ? Z_OFF : (A1_OFF + c * 16);
    const int a3step = (c < 3) ? 96 : 0;
    const int a3base = (c < 3) ? (A3_OFF + (hi * 3 + c) * 16) : Z_OFF;

    const int gwave = blockIdx.x * 16 + (tid >> 6);

    // ================= steady state: 32 rows/chunk (r6 geometry) ================
    for (int chunk = gwave; chunk < NCHUNK; chunk += NWAVE_TOT) {
        // x load (no prefetch: 4 waves/SIMD of TLP hide the HBM latency)
        const float* xp = x + (size_t)(chunk * 32 + c) * 9;
        float a0 = xp[0], a1 = xp[1], a2v = xp[2], a3 = xp[3], a4 = xp[4];
        float a5 = xp[5], a6 = xp[6], a7 = xp[7], a8 = xp[8];
        float d0 = a0 - a3, d1 = a1 - a4, d2 = a2v - a5;
        float e0 = a0 - a6, e1 = a1 - a7, e2 = a2v - a8;
        float f0 = a3 - a6, f1 = a4 - a7, f2 = a5 - a8;
        float q0 = sqrtf(fmaf(d0, d0, fmaf(d1, d1, d2 * d2)));
        float q1 = sqrtf(fmaf(e0, e0, fmaf(e1, e1, e2 * e2)));
        float q2 = sqrtf(fmaf(f0, f0, fmaf(f1, f1, f2 * f2)));

        // layer-1 B-frag: B[k][col=c] = {q0,q1,q2,1,0...} on lo lanes
        union { short8 s8; uint32_t u[4]; } qf;
        qf.u[0] = hi ? 0u : cvtpk(q0, q1);
        qf.u[1] = hi ? 0u : cvtpk(q2, 1.0f);
        qf.u[2] = 0; qf.u[3] = 0;
        const short8 qfrag = qf.s8;

        // acc init = b2 via bias-MFMA
        f32x16 acc[8];
#pragma unroll
        for (int mt = 0; mt < 8; ++mt) {
            union { short8 s8; uint32_t u[4]; } bA;
            bA.u[0] = b2pk[mt]; bA.u[1] = 0; bA.u[2] = 0; bA.u[3] = 0;
            acc[mt] = __builtin_amdgcn_mfma_f32_32x32x16_bf16(bA.s8, biasB, Z, 0, 0, 0);
        }

        // layer-1 tile -> pack -> layer-2, one 32-unit h1-tile at a time
#pragma unroll
        for (int tau = 0; tau < 8; ++tau) {
            short8 a1f = *(const short8*)(smem + a1base + tau * a1step);
            f32x16 d1v = __builtin_amdgcn_mfma_f32_32x32x16_bf16(a1f, qfrag, Z, 0, 0, 0);
#pragma unroll
            for (int p = 0; p < 2; ++p) {
                const int kt = 2 * tau + p;
                union { short8 s8; uint32_t u[4]; } pk;
#pragma unroll
                for (int w = 0; w < 4; ++w)
                    pk.u[w] = cvtpk(fmaxf(d1v[8 * p + 2 * w], 0.0f),
                                    fmaxf(d1v[8 * p + 2 * w + 1], 0.0f));
                const short8 bfr = pk.s8;
#pragma unroll
                for (int mt = 0; mt < 8; ++mt) {
                    short8 a2 = *(const short8*)(smem + (size_t)(kt * 8 + mt) * 1024 + l * 16);
                    acc[mt] = __builtin_amdgcn_mfma_f32_32x32x16_bf16(a2, bfr, acc[mt], 0, 0, 0);
                }
            }
        }

        // layer-3: 16 MFMAs; B3-frag for kt' = relu(acc[kt'>>1] regs 8*(kt'&1)..+7)
        f32x16 d3 = Z;
#pragma unroll
        for (int kt3 = 0; kt3 < 16; ++kt3) {
            const int mt = kt3 >> 1, p = kt3 & 1;
            union { short8 s8; uint32_t u[4]; } pk;
#pragma unroll
            for (int w = 0; w < 4; ++w)
                pk.u[w] = cvtpk(fmaxf(acc[mt][8 * p + 2 * w], 0.0f),
                                fmaxf(acc[mt][8 * p + 2 * w + 1], 0.0f));
            short8 a3f = *(const short8*)(smem + a3base + kt3 * a3step);
            d3 = __builtin_amdgcn_mfma_f32_32x32x16_bf16(a3f, pk.s8, d3, 0, 0, 0);
        }

        // eigen + store: lo lanes hold d3 regs 0,1,2 = (w00,w11,w01) for batch col c
        if (hi == 0) {
            float w0 = d3[0] + b30, w1v = d3[1] + b31, wc = d3[2] + b32;
            float mm = 0.5f * (w0 + w1v), dd = 0.5f * (w0 - w1v);
            float rad = sqrtf(fmaf(dd, dd, wc * wc));
            *(float2*)(out + (size_t)(chunk * 32 + c) * 2) = make_float2(mm - rad, mm + rad);
        }
    }
}

extern "C" void kernel_launch(void* const* d_in, const int* in_sizes, int n_in,
                              void* d_out, int out_size, void* d_ws, size_t ws_size,
                              hipStream_t stream) {
    const float* x  = (const float*)d_in[0];
    const float* W1 = (const float*)d_in[1];
    const float* b1 = (const float*)d_in[2];
    const float* W2 = (const float*)d_in[3];
    const float* b2 = (const float*)d_in[4];
    const float* W3 = (const float*)d_in[5];
    const float* b3 = (const float*)d_in[6];
    float* out = (float*)d_out;

    (void)d_ws; (void)ws_size;

    (void)hipFuncSetAttribute((const void*)fused_kernel,
                              hipFuncAttributeMaxDynamicSharedMemorySize, LDS_TOTAL);

    fused_kernel<<<NBLK, NTHR, LDS_TOTAL, stream>>>(x, W1, b1, W2, b2, W3, b3, out);
}

// Round 10
// 142.596 us; speedup vs baseline: 9.5911x; 9.5911x over previous
//
#include <hip/hip_runtime.h>
#include <hip/hip_bf16.h>
#include <stdint.h>

typedef __attribute__((ext_vector_type(8)))  short short8;
typedef __attribute__((ext_vector_type(16))) float f32x16;

#define NROWS 500000
#define NCHUNK 15625         // 500000 / 32 rows per chunk (exact, no tail)
#define NBLK 256
#define NTHR 512
#define NWAVE_TOT (NBLK * 8)

// swap bits 2<->3 (involution); aligns MFMA D-layout (row=(reg&3)+8(reg>>2)+4hi)
// with B-frag k-layout (k = 16kt + 8hi + j). HW-verified r6 (absmax 0.047).
#define SW(v) ((((v) & ~12u)) | (((v) & 4u) << 1) | (((v) & 8u) >> 1))

// LDS map (bytes) — identical to r6
#define A2_OFF   0           // 131072 : W2 A-frags, frag(kt,mt) @ (kt*8+mt)*1024 + l*16
#define A1_OFF   131072      // 4096   : [W1t|b1] A-frags, lo lanes only: fr*512 + c*16
#define Z_OFF    135168      // 16     : shared zero block (broadcast reads)
#define A3_OFF   135184      // 1536   : W3 A-frags: kt*96 + (hi*3+c)*16 (c<3)
#define SCR_OFF  136720      // 16384  : packing scratch (16 W2 rows fp32)
#define LDS_TOTAL 153104

__device__ __forceinline__ uint32_t cvtpk(float lo, float hi) {
    uint32_t r;
    asm("v_cvt_pk_bf16_f32 %0, %1, %2" : "=v"(r) : "v"(lo), "v"(hi));
    return r;
}

__global__ __launch_bounds__(NTHR, 2) void fused_kernel(
    const float* __restrict__ x,  const float* __restrict__ W1,
    const float* __restrict__ b1, const float* __restrict__ W2,
    const float* __restrict__ b2, const float* __restrict__ W3,
    const float* __restrict__ b3, float* __restrict__ out)
{
    extern __shared__ char smem[];
    uint4* frag4 = (uint4*)(smem + A2_OFF);
    float* scrf  = (float*)(smem + SCR_OFF);
    uint4* scr4  = (uint4*)(smem + SCR_OFF);

    const int tid = threadIdx.x;
    const int l   = tid & 63;
    const int hi  = l >> 5;       // k-half within frags
    const int c   = l & 31;       // batch column / A-row within tile

    // ================= one-time packing (r6 machinery, HW-verified) =============
    {
        int fr = tid >> 6, l2 = tid & 63;
        if (l2 < 32) {
            int row = fr * 32 + l2;
            uint4 v;
            v.x = cvtpk(W1[row], W1[256 + row]);
            v.y = cvtpk(W1[512 + row], b1[row]);
            v.z = 0; v.w = 0;
            ((uint4*)(smem + A1_OFF))[fr * 32 + l2] = v;
        }
        if (tid == 511) ((uint4*)(smem + Z_OFF))[0] = make_uint4(0, 0, 0, 0);
        if (tid < 96) {
            int fr3 = tid / 6, rem = tid % 6, hi2 = rem / 3, c2 = rem % 3;
            int kb = 16 * fr3 + 8 * hi2;
            uint4 v;
            v.x = cvtpk(W3[(kb + 0) * 3 + c2], W3[(kb + 1) * 3 + c2]);
            v.y = cvtpk(W3[(kb + 2) * 3 + c2], W3[(kb + 3) * 3 + c2]);
            v.z = cvtpk(W3[(kb + 4) * 3 + c2], W3[(kb + 5) * 3 + c2]);
            v.w = cvtpk(W3[(kb + 6) * 3 + c2], W3[(kb + 7) * 3 + c2]);
            ((uint4*)(smem + A3_OFF))[fr3 * 6 + rem] = v;
        }
    }
    const uint4* gw2 = (const uint4*)W2;
    for (int kt = 0; kt < 16; ++kt) {
        __syncthreads();
        scr4[tid]       = gw2[kt * 1024 + tid];
        scr4[tid + 512] = gw2[kt * 1024 + 512 + tid];
        __syncthreads();
        int mt = tid >> 6, l2 = tid & 63, hi2 = l2 >> 5, c2 = l2 & 31;
        int col = 32 * mt + (int)SW((unsigned)c2);
        float f[8];
#pragma unroll
        for (int j = 0; j < 8; ++j) {
            int lrow = 8 * (j >> 2) + 4 * hi2 + (j & 3);
            f[j] = scrf[lrow * 256 + col];
        }
        uint4 v;
        v.x = cvtpk(f[0], f[1]); v.y = cvtpk(f[2], f[3]);
        v.z = cvtpk(f[4], f[5]); v.w = cvtpk(f[6], f[7]);
        frag4[(kt * 8 + mt) * 64 + l2] = v;
    }
    __syncthreads();   // LDS read-only from here; waves fully independent

    // ================= per-lane held constants =================
    const f32x16 Z = {0,0,0,0,0,0,0,0,0,0,0,0,0,0,0,0};
    uint32_t b2pk[8];                 // bf16(b2[SW(32mt+c)]), lo lanes only
#pragma unroll
    for (int mt = 0; mt < 8; ++mt)
        b2pk[mt] = hi ? 0u : cvtpk(b2[32 * mt + (int)SW((unsigned)c)], 0.0f);
    union { short8 s8; uint32_t u[4]; } bB;   // bias B-frag: B[0][*]=1 (lo lanes)
    bB.u[0] = hi ? 0u : 0x3F80u; bB.u[1] = 0; bB.u[2] = 0; bB.u[3] = 0;
    const short8 biasB = bB.s8;
    const float b30 = b3[0], b31 = b3[1], b32 = b3[2];

    const int a1step = hi ? 0 : 512;
    const int a1base = hi ? Z_OFF : (A1_OFF + c * 16);
    const int a3step = (c < 3) ? 96 : 0;
    const int a3base = (c < 3) ? (A3_OFF + (hi * 3 + c) * 16) : Z_OFF;

    const int gwave = blockIdx.x * 8 + (tid >> 6);

    // x staging (double-buffered, r6 pattern)
    float xb[9], xn[9];
    {
        const float* xp = x + (size_t)(gwave * 32 + c) * 9;
#pragma unroll
        for (int j = 0; j < 9; ++j) xb[j] = xp[j];
    }

    // ================= steady state: 32 rows/chunk, ILP-pipelined ===============
    for (int chunk = gwave; chunk < NCHUNK; chunk += NWAVE_TOT) {
        // prefetch next chunk's x
        {
            int nxt = chunk + NWAVE_TOT; if (nxt >= NCHUNK) nxt = chunk;
            const float* xpn = x + (size_t)(nxt * 32 + c) * 9;
#pragma unroll
            for (int j = 0; j < 9; ++j) xn[j] = xpn[j];
        }
        // bond lengths -> layer-1 B-frag
        float d0 = xb[0] - xb[3], d1 = xb[1] - xb[4], d2 = xb[2] - xb[5];
        float e0 = xb[0] - xb[6], e1 = xb[1] - xb[7], e2 = xb[2] - xb[8];
        float f0 = xb[3] - xb[6], f1 = xb[4] - xb[7], f2 = xb[5] - xb[8];
        float q0 = sqrtf(fmaf(d0, d0, fmaf(d1, d1, d2 * d2)));
        float q1 = sqrtf(fmaf(e0, e0, fmaf(e1, e1, e2 * e2)));
        float q2 = sqrtf(fmaf(f0, f0, fmaf(f1, f1, f2 * f2)));
        union { short8 s8; uint32_t u[4]; } qf;
        qf.u[0] = hi ? 0u : cvtpk(q0, q1);
        qf.u[1] = hi ? 0u : cvtpk(q2, 1.0f);
        qf.u[2] = 0; qf.u[3] = 0;
        const short8 qfrag = qf.s8;

        // issue L1 for tau=0 FIRST; bias-MFMAs below hide its latency
        short8 a1f = *(const short8*)(smem + a1base);
        f32x16 d1v = __builtin_amdgcn_mfma_f32_32x32x16_bf16(a1f, qfrag, Z, 0, 0, 0);

        // acc init = b2 via bias-MFMA (8 independent)
        f32x16 acc[8];
#pragma unroll
        for (int mt = 0; mt < 8; ++mt) {
            union { short8 s8; uint32_t u[4]; } bA;
            bA.u[0] = b2pk[mt]; bA.u[1] = 0; bA.u[2] = 0; bA.u[3] = 0;
            acc[mt] = __builtin_amdgcn_mfma_f32_32x32x16_bf16(bA.s8, biasB, Z, 0, 0, 0);
        }

        // pipelined: pack both kt from d1v, re-issue L1 into d1v, then 16 L2 MFMAs
#pragma unroll
        for (int tau = 0; tau < 8; ++tau) {
            short8 bfr0, bfr1;
            {
                union { short8 s8; uint32_t u[4]; } pk;
#pragma unroll
                for (int w = 0; w < 4; ++w)
                    pk.u[w] = cvtpk(fmaxf(d1v[2 * w], 0.0f), fmaxf(d1v[2 * w + 1], 0.0f));
                bfr0 = pk.s8;
#pragma unroll
                for (int w = 0; w < 4; ++w)
                    pk.u[w] = cvtpk(fmaxf(d1v[8 + 2 * w], 0.0f), fmaxf(d1v[8 + 2 * w + 1], 0.0f));
                bfr1 = pk.s8;
            }
            if (tau < 7) {   // issue next tau's L1 now; latency hides under L2 MFMAs
                short8 a1n = *(const short8*)(smem + a1base + (tau + 1) * a1step);
                d1v = __builtin_amdgcn_mfma_f32_32x32x16_bf16(a1n, qfrag, Z, 0, 0, 0);
            }
            const int kt0 = 2 * tau, kt1 = 2 * tau + 1;
#pragma unroll
            for (int mt = 0; mt < 8; ++mt) {
                short8 a2 = *(const short8*)(smem + (size_t)(kt0 * 8 + mt) * 1024 + l * 16);
                acc[mt] = __builtin_amdgcn_mfma_f32_32x32x16_bf16(a2, bfr0, acc[mt], 0, 0, 0);
            }
#pragma unroll
            for (int mt = 0; mt < 8; ++mt) {
                short8 a2 = *(const short8*)(smem + (size_t)(kt1 * 8 + mt) * 1024 + l * 16);
                acc[mt] = __builtin_amdgcn_mfma_f32_32x32x16_bf16(a2, bfr1, acc[mt], 0, 0, 0);
            }
        }

        // layer-3: dual parity chains (d3b's regs reuse dead acc[0] — no AGPR growth)
        f32x16 d3a, d3b;
        {
            union { short8 s8; uint32_t u[4]; } pk;
#pragma unroll
            for (int w = 0; w < 4; ++w)
                pk.u[w] = cvtpk(fmaxf(acc[0][2 * w], 0.0f), fmaxf(acc[0][2 * w + 1], 0.0f));
            short8 a3f = *(const short8*)(smem + a3base);
            d3a = __builtin_amdgcn_mfma_f32_32x32x16_bf16(a3f, pk.s8, Z, 0, 0, 0);
#pragma unroll
            for (int w = 0; w < 4; ++w)
                pk.u[w] = cvtpk(fmaxf(acc[0][8 + 2 * w], 0.0f), fmaxf(acc[0][8 + 2 * w + 1], 0.0f));
            short8 a3g = *(const short8*)(smem + a3base + a3step);
            d3b = __builtin_amdgcn_mfma_f32_32x32x16_bf16(a3g, pk.s8, Z, 0, 0, 0);
        }
#pragma unroll
        for (int kt3 = 2; kt3 < 16; ++kt3) {
            const int mt = kt3 >> 1, p = kt3 & 1;
            union { short8 s8; uint32_t u[4]; } pk;
#pragma unroll
            for (int w = 0; w < 4; ++w)
                pk.u[w] = cvtpk(fmaxf(acc[mt][8 * p + 2 * w], 0.0f),
                                fmaxf(acc[mt][8 * p + 2 * w + 1], 0.0f));
            short8 a3f = *(const short8*)(smem + a3base + kt3 * a3step);
            if (kt3 & 1)
                d3b = __builtin_amdgcn_mfma_f32_32x32x16_bf16(a3f, pk.s8, d3b, 0, 0, 0);
            else
                d3a = __builtin_amdgcn_mfma_f32_32x32x16_bf16(a3f, pk.s8, d3a, 0, 0, 0);
        }

        // eigen + store: lo lanes hold regs 0,1,2 = (w00,w11,w01) for batch col c
        if (hi == 0) {
            float w0  = (d3a[0] + d3b[0]) + b30;
            float w1v = (d3a[1] + d3b[1]) + b31;
            float wc  = (d3a[2] + d3b[2]) + b32;
            float mm = 0.5f * (w0 + w1v), dd = 0.5f * (w0 - w1v);
            float rad = sqrtf(fmaf(dd, dd, wc * wc));
            *(float2*)(out + (size_t)(chunk * 32 + c) * 2) = make_float2(mm - rad, mm + rad);
        }

        // rotate prefetched x
#pragma unroll
        for (int j = 0; j < 9; ++j) xb[j] = xn[j];
    }
}

extern "C" void kernel_launch(void* const* d_in, const int* in_sizes, int n_in,
                              void* d_out, int out_size, void* d_ws, size_t ws_size,
                              hipStream_t stream) {
    const float* x  = (const float*)d_in[0];
    const float* W1 = (const float*)d_in[1];
    const float* b1 = (const float*)d_in[2];
    const float* W2 = (const float*)d_in[3];
    const float* b2 = (const float*)d_in[4];
    const float* W3 = (const float*)d_in[5];
    const float* b3 = (const float*)d_in[6];
    float* out = (float*)d_out;

    (void)d_ws; (void)ws_size;

    (void)hipFuncSetAttribute((const void*)fused_kernel,
                              hipFuncAttributeMaxDynamicSharedMemorySize, LDS_TOTAL);

    fused_kernel<<<NBLK, NTHR, LDS_TOTAL, stream>>>(x, W1, b1, W2, b2, W3, b3, out);
}